// Round 18
// baseline (707.340 us; speedup 1.0000x reference)
//
#include <hip/hip_runtime.h>

constexpr int NC = 100000;
constexpr int NQ = 20000;
constexpr int FC = 300;
constexpr int FQ = 768;
constexpr int NEDGE = 400000;
constexpr int NTOT = NC + NC + NQ;   // concatenated dst segments: et0 | et1 | et2
constexpr int NTOT2 = NC + NQ;       // all nodes (context then question)
constexpr int NB0 = (NC + 127) / 128;  // 782
constexpr int NB1 = (NQ + 127) / 128;  // 157
constexpr int NBALL = NB0 + NB1;       // 939
constexpr int NBC64 = (NC + 63) / 64;  // 1563
constexpr int NBQ64 = (NQ + 63) / 64;  // 313
constexpr int NBALL64 = NBC64 + NBQ64; // 1876
constexpr int NSCAT = (3 * NEDGE + 255) / 256;  // 4688 scatter blocks
constexpr float SCALE = 0.17677669529663687f;  // 1/sqrt(32)
constexpr float LOG2E = 1.4426950408889634f;

typedef __attribute__((ext_vector_type(8))) short bf16x8;
typedef __attribute__((ext_vector_type(4))) float f32x4;
typedef unsigned short u16;

__device__ __forceinline__ float gelu_f(float x) {
  return 0.5f * x * (1.0f + erff(x * 0.7071067811865476f));
}
__device__ __forceinline__ u16 bf16_rne(float x) {
  unsigned u = __float_as_uint(x);
  unsigned r = u + 0x7fffu + ((u >> 16) & 1u);
  return (u16)(r >> 16);
}
__device__ __forceinline__ float bf16_to_f(u16 h) {
  return __uint_as_float(((unsigned)h) << 16);
}
__device__ __forceinline__ void split2(float x, u16& hi, u16& lo) {
  hi = bf16_rne(x);
  lo = bf16_rne(x - bf16_to_f(hi));
}
__device__ __forceinline__ void splitT(float x, u16& hi, u16& lo) {
  hi = (u16)(__float_as_uint(x) >> 16);
  lo = bf16_rne(x - bf16_to_f(hi));
}

// ---------------- CSR scan pieces ----------------
__global__ void k_scan_block(const int* __restrict__ in, int* __restrict__ out,
                             int* __restrict__ bsum, int n) {
  __shared__ int s[256];
  int tid = threadIdx.x;
  int i = blockIdx.x * 256 + tid;
  int v = (i < n) ? in[i] : 0;
  s[tid] = v;
  __syncthreads();
  for (int off = 1; off < 256; off <<= 1) {
    int t = (tid >= off) ? s[tid - off] : 0;
    __syncthreads();
    s[tid] += t;
    __syncthreads();
  }
  if (i < n) out[i] = s[tid] - v;
  if (tid == 255) bsum[blockIdx.x] = s[255];
}

__global__ void k_scan_sums(int* __restrict__ bsum, int nb) {
  __shared__ int s[1024];
  int tid = threadIdx.x;
  int v = (tid < nb) ? bsum[tid] : 0;
  s[tid] = v;
  __syncthreads();
  for (int off = 1; off < 1024; off <<= 1) {
    int t = (tid >= off) ? s[tid - off] : 0;
    __syncthreads();
    s[tid] += t;
    __syncthreads();
  }
  if (tid < nb) bsum[tid] = s[tid] - v;
}

__global__ void k_scan_add(int* __restrict__ ptr, const int* __restrict__ bsum,
                           int* __restrict__ cursor, int n, int total) {
  int i = blockIdx.x * 256 + threadIdx.x;
  if (i < n) {
    int v = ptr[i] + bsum[blockIdx.x];
    ptr[i] = v;
    cursor[i] = v;
  }
  if (i == 0) ptr[n] = total;
}

// ---------------- B prep for BOTH layers: 20 slabs + fused edge counting --------------------
__global__ void prep_all(const float* __restrict__ kW, const float* __restrict__ kB,
                         const float* __restrict__ qW, const float* __restrict__ qB,
                         const float* __restrict__ vW, const float* __restrict__ vB,
                         const float* __restrict__ aW, const float* __restrict__ aB,
                         const float* __restrict__ arel, const float* __restrict__ mrel,
                         const float* __restrict__ prel,
                         u16* __restrict__ Bth, u16* __restrict__ Btl,
                         float* __restrict__ biasOut,
                         const int* __restrict__ d0, const int* __restrict__ d1,
                         const int* __restrict__ d2, int* __restrict__ counts) {
  int i = blockIdx.x;     // input dim 0..127
  int col = threadIdx.x;  // output col 0..127
  int y = blockIdx.y;     // 0..19
  // fused edge counting (counts zeroed by split_in, which runs before this kernel)
  {
    const int nth = 20 * 128 * 128;
    int gtid = (y * 128 + i) * 128 + col;
    for (int e = gtid; e < 3 * NEDGE; e += nth) {
      int et = e / NEDGE, ee = e - et * NEDGE;
      int d = (et == 0) ? d0[ee] : (et == 1) ? d1[ee] : d2[ee];
      int base = (et == 0) ? 0 : (et == 1) ? NC : 2 * NC;
      atomicAdd(&counts[base + d], 1);
    }
  }
  int l = y / 10, yy = y % 10;
  size_t lw = (size_t)l * 2 * 16384, lb = (size_t)l * 2 * 128;
  size_t le = (size_t)l * 3 * 4096, lp = (size_t)l * 3 * 4;
  const float *W = nullptr, *bb = nullptr, *rel = nullptr, *pr = nullptr;
  float mscale = 1.0f;
  bool fold = false;
  switch (yy) {
    case 0: W = qW + lw; bb = qB + lb; break;
    case 1: fold = true; W = kW + lw; bb = kB + lb; rel = arel + le + 4096; pr = prel + lp + 4; mscale = SCALE; break;
    case 2: fold = true; W = vW + lw; bb = vB + lb; rel = mrel + le + 4096; break;
    case 3: fold = true; W = kW + lw; bb = kB + lb; rel = arel + le + 8192; pr = prel + lp + 8; mscale = SCALE; break;
    case 4: fold = true; W = vW + lw; bb = vB + lb; rel = mrel + le + 8192; break;
    case 5: W = qW + lw + 16384; bb = qB + lb + 128; break;
    case 6: fold = true; W = kW + lw + 16384; bb = kB + lb + 128; rel = arel + le; pr = prel + lp; mscale = SCALE; break;
    case 7: fold = true; W = vW + lw + 16384; bb = vB + lb + 128; rel = mrel + le; break;
    case 8: W = aW + lw; bb = aB + lb; break;
    default: W = aW + lw + 16384; bb = aB + lb + 128; break;
  }
  int colOff = y * 128;
  if (!fold) {
    float v = W[i * 128 + col];
    u16 hi, lo;
    split2(v, hi, lo);
    Bth[(size_t)(colOff + col) * 128 + i] = hi;
    Btl[(size_t)(colOff + col) * 128 + i] = lo;
    if (i == 0) biasOut[colOff + col] = bb[col];
    return;
  }
  int h = col >> 5, f = col & 31;
  float m = (pr ? pr[h] : 1.0f) * mscale;
  float s = 0.0f;
  #pragma unroll
  for (int d = 0; d < 32; ++d)
    s += W[i * 128 + h * 32 + d] * rel[(h * 32 + d) * 32 + f];
  s *= m;
  u16 hi, lo;
  split2(s, hi, lo);
  Bth[(size_t)(colOff + col) * 128 + i] = hi;
  Btl[(size_t)(colOff + col) * 128 + i] = lo;
  if (i == 0) {
    float sb = 0.0f;
    #pragma unroll
    for (int d = 0; d < 32; ++d)
      sb += bb[h * 32 + d] * rel[(h * 32 + d) * 32 + f];
    biasOut[colOff + col] = sb * m;
  }
}

// ---------------- input weight split (+ zeroes counts for the fused counting) ---------------
__global__ void split_in(const float* __restrict__ Wc, const float* __restrict__ bc,
                         const float* __restrict__ Wq, const float* __restrict__ bq,
                         u16* __restrict__ Bth, u16* __restrict__ Btl,
                         float* __restrict__ biasOut, int* __restrict__ counts) {
  int n = blockIdx.x, y = blockIdx.y;
  {
    const int nth = 2 * 128 * 256;
    int gtid = (y * 128 + n) * 256 + threadIdx.x;
    for (int i = gtid; i < NTOT; i += nth) counts[i] = 0;
  }
  const float* W = y ? Wq : Wc;
  const float* b = y ? bq : bc;
  int K = y ? FQ : FC, Kp = y ? 768 : 320;
  size_t boff = y ? (size_t)128 * 320 : 0;
  for (int k = threadIdx.x; k < Kp; k += 256) {
    float v = (k < K) ? W[(size_t)k * 128 + n] : 0.0f;
    u16 hi, lo;
    split2(v, hi, lo);
    Bth[boff + (size_t)n * Kp + k] = hi;
    Btl[boff + (size_t)n * Kp + k] = lo;
  }
  if (threadIdx.x == 0) biasOut[(y ? 128 : 0) + n] = b[n];
}

// ---------------- fused scatter + input projection ------------------------------------------
// Blocks [0,NSCAT): edge scatter.  Blocks [NSCAT, NSCAT+NBALL64): f32-A GEMM (BM=64).
__global__ __launch_bounds__(256) void pipe_gemm(
    const float* __restrict__ Ac, const float* __restrict__ Aq,
    const u16* __restrict__ Bth, const u16* __restrict__ Btl,
    const float* __restrict__ biasBuf,
    u16* __restrict__ xh_all, u16* __restrict__ xl_all,
    const int* __restrict__ s0, const int* __restrict__ s1, const int* __restrict__ s2,
    const int* __restrict__ d0, const int* __restrict__ d1, const int* __restrict__ d2,
    int* __restrict__ cursor, int* __restrict__ srcs_out) {
  __shared__ u16 smem[15360];  // Ah@0 Al@2560 Bh@5120 Bl@10240 ; epilogue reuses @0 [64][136]
  constexpr int AH = 0, AL = 2560, BH = 5120, BL = 10240;
  const int tid = threadIdx.x;

  if (blockIdx.x < NSCAT) {
    int i = blockIdx.x * 256 + tid;
    if (i < 3 * NEDGE) {
      int et = i / NEDGE, e = i - et * NEDGE;
      int d = (et == 0) ? d0[e] : (et == 1) ? d1[e] : d2[e];
      int sv = (et == 0) ? s0[e] : (et == 1) ? s1[e] : s2[e];
      int base = (et == 0) ? 0 : (et == 1) ? NC : 2 * NC;
      int p = atomicAdd(&cursor[base + d], 1);
      srcs_out[p] = sv;
    }
    return;
  }

  const int lane = tid & 63, wv = tid >> 6;
  const int l15 = lane & 15, g4 = lane >> 4, koff = g4 * 8;
  const int srA = tid >> 2, scA = (tid & 3) * 8;   // A: 8 f32/thread
  const int srB = tid >> 1, scB = (tid & 1) * 16;  // B: 16 u16/thread/array

  const int bid = blockIdx.x - NSCAT;
  const int nt = (bid < NBC64) ? 0 : 1;
  const int m0 = nt ? (bid - NBC64) * 64 : bid * 64;
  const int M = nt ? NQ : NC;
  const int rowbase = nt ? NC : 0;
  const float* A32;
  int K, Kp, biasOff;
  size_t boff;
  if (nt == 0) { A32 = Ac; K = FC; Kp = 320; boff = 0; biasOff = 0; }
  else { A32 = Aq; K = FQ; Kp = 768; boff = (size_t)128 * 320; biasOff = 128; }
  size_t arow = (size_t)(m0 + srA) * K;
  const bool rowokA = (m0 + srA) < M;
  const int nk = (K + 31) / 32;

  f32x4 acc[8];
  #pragma unroll
  for (int ni = 0; ni < 8; ++ni) acc[ni] = (f32x4){0.f, 0.f, 0.f, 0.f};

  auto loadA = [&](float va[8], int k0) {
    if (rowokA && (k0 + 32 <= K)) {
      const float* ap = A32 + arow + k0 + scA;
      float4 f0 = *(const float4*)ap;
      float4 f1 = *(const float4*)(ap + 4);
      va[0] = f0.x; va[1] = f0.y; va[2] = f0.z; va[3] = f0.w;
      va[4] = f1.x; va[5] = f1.y; va[6] = f1.z; va[7] = f1.w;
    } else {
      #pragma unroll
      for (int j = 0; j < 8; ++j) {
        int kc = k0 + scA + j;
        va[j] = (rowokA && kc < K) ? A32[arow + kc] : 0.0f;
      }
    }
  };
  auto loadB = [&](uint4& bh0, uint4& bh1, uint4& bl0, uint4& bl1, int k0) {
    const u16* bp = Bth + boff + (size_t)srB * Kp + k0 + scB;
    bh0 = *(const uint4*)bp;
    bh1 = *(const uint4*)(bp + 8);
    const u16* lp = Btl + boff + (size_t)srB * Kp + k0 + scB;
    bl0 = *(const uint4*)lp;
    bl1 = *(const uint4*)(lp + 8);
  };

  float vaC[8], vaN[8], vaN2[8];
  uint4 bhC0, bhC1, blC0, blC1, bhN0, bhN1, blN0, blN1;
  loadA(vaC, 0);
  loadB(bhC0, bhC1, blC0, blC1, 0);
  if (nk > 1) loadA(vaN, 32);

  for (int ks = 0; ks < nk; ++ks) {
    {
      alignas(16) u16 hv[8], lv[8];
      #pragma unroll
      for (int j = 0; j < 8; ++j) splitT(vaC[j], hv[j], lv[j]);
      *(uint4*)&smem[AH + srA * 40 + scA] = *(const uint4*)hv;
      *(uint4*)&smem[AL + srA * 40 + scA] = *(const uint4*)lv;
      *(uint4*)&smem[BH + srB * 40 + scB] = bhC0;
      *(uint4*)&smem[BH + srB * 40 + scB + 8] = bhC1;
      *(uint4*)&smem[BL + srB * 40 + scB] = blC0;
      *(uint4*)&smem[BL + srB * 40 + scB + 8] = blC1;
    }
    __syncthreads();

    const bool moreA2 = (ks + 2) < nk;
    const bool moreB = (ks + 1) < nk;
    if (moreA2) loadA(vaN2, (ks + 2) * 32);
    if (moreB) loadB(bhN0, bhN1, blN0, blN1, (ks + 1) * 32);

    {
      int row = wv * 16 + l15;
      bf16x8 a_h = *(const bf16x8*)&smem[AH + row * 40 + koff];
      bf16x8 a_l = *(const bf16x8*)&smem[AL + row * 40 + koff];
      #pragma unroll
      for (int ni = 0; ni < 8; ++ni) {
        int col = ni * 16 + l15;
        bf16x8 b_h = *(const bf16x8*)&smem[BH + col * 40 + koff];
        bf16x8 b_l = *(const bf16x8*)&smem[BL + col * 40 + koff];
        acc[ni] = __builtin_amdgcn_mfma_f32_16x16x32_bf16(a_h, b_h, acc[ni], 0, 0, 0);
        acc[ni] = __builtin_amdgcn_mfma_f32_16x16x32_bf16(a_l, b_h, acc[ni], 0, 0, 0);
        acc[ni] = __builtin_amdgcn_mfma_f32_16x16x32_bf16(a_h, b_l, acc[ni], 0, 0, 0);
      }
    }
    __syncthreads();

    if (moreB) {
      #pragma unroll
      for (int j = 0; j < 8; ++j) vaC[j] = vaN[j];
      bhC0 = bhN0; bhC1 = bhN1; blC0 = blN0; blC1 = blN1;
    }
    if (moreA2) {
      #pragma unroll
      for (int j = 0; j < 8; ++j) vaN[j] = vaN2[j];
    }
  }

  const int rl0 = wv * 16 + g4 * 4;
  #pragma unroll
  for (int ni = 0; ni < 8; ++ni) {
    float bi = biasBuf[biasOff + ni * 16 + l15];
    #pragma unroll
    for (int rr = 0; rr < 4; ++rr)
      acc[ni][rr] = fmaxf(acc[ni][rr] + bi, 0.0f);
  }

  const int wrow = tid >> 2, wseg = tid & 3;
  #pragma unroll
  for (int ph = 0; ph < 2; ++ph) {
    if (ph) __syncthreads();
    #pragma unroll
    for (int ni = 0; ni < 8; ++ni) {
      #pragma unroll
      for (int rr = 0; rr < 4; ++rr) {
        u16 hh, ll;
        split2(acc[ni][rr], hh, ll);
        smem[(rl0 + rr) * 136 + ni * 16 + l15] = ph ? ll : hh;
      }
    }
    __syncthreads();
    int grow = m0 + wrow;
    if (grow < M) {
      u16* dstp = ph ? xl_all : xh_all;
      uint4* dst = (uint4*)&dstp[(size_t)(rowbase + grow) * 128 + wseg * 32];
      const uint4* src = (const uint4*)&smem[wrow * 136 + wseg * 32];
      #pragma unroll
      for (int j = 0; j < 4; ++j) dst[j] = src[j];
    }
  }
}

// ---------------- a-projection GEMM: pre-gelu'd bf16 A (from attn), 2-term B, skip-gate -----
__global__ __launch_bounds__(256) void aproj_gemm(
    const u16* __restrict__ Ag,     // gelu(agg) bf16 [NTOT2 x 128]
    const u16* __restrict__ Bth, const u16* __restrict__ Btl,
    const float* __restrict__ biasBuf,
    u16* __restrict__ xh_all, u16* __restrict__ xl_all,
    const float* __restrict__ skip, int l) {
  __shared__ u16 smem[15360];  // Ah@0, Bh@5120, Bl@10240; epilogue reuses [64][136]
  constexpr int AH = 0, BHo = 5120, BLo = 10240;
  const int tid = threadIdx.x, lane = tid & 63, wv = tid >> 6;
  const int l15 = lane & 15, g4 = lane >> 4, koff = g4 * 8;
  const int sr = tid >> 1, sc = (tid & 1) * 16;

  const int bid = blockIdx.x;
  const int nt = (bid < NB0) ? 0 : 1;
  const int m0 = nt ? (bid - NB0) * 128 : bid * 128;
  const int M = nt ? NQ : NC;
  const int rowbase = nt ? NC : 0;
  const size_t boff = (size_t)(8 + nt) * 16384;
  const int biasOff = (8 + nt) * 128;
  const bool rowok = (m0 + sr) < M;

  f32x4 acc[2][8];
  #pragma unroll
  for (int mi = 0; mi < 2; ++mi)
    #pragma unroll
    for (int ni = 0; ni < 8; ++ni) acc[mi][ni] = (f32x4){0.f, 0.f, 0.f, 0.f};

  for (int k0 = 0; k0 < 128; k0 += 32) {
    uint4 h0 = {0, 0, 0, 0}, h1 = {0, 0, 0, 0};
    if (rowok) {
      const u16* ap = Ag + (size_t)(rowbase + m0 + sr) * 128 + k0 + sc;
      h0 = *(const uint4*)ap;
      h1 = *(const uint4*)(ap + 8);
    }
    *(uint4*)&smem[AH + sr * 40 + sc] = h0;
    *(uint4*)&smem[AH + sr * 40 + sc + 8] = h1;
    {
      const u16* bp = Bth + boff + (size_t)sr * 128 + k0 + sc;
      *(uint4*)&smem[BHo + sr * 40 + sc] = *(const uint4*)bp;
      *(uint4*)&smem[BHo + sr * 40 + sc + 8] = *(const uint4*)(bp + 8);
      const u16* lp = Btl + boff + (size_t)sr * 128 + k0 + sc;
      *(uint4*)&smem[BLo + sr * 40 + sc] = *(const uint4*)lp;
      *(uint4*)&smem[BLo + sr * 40 + sc + 8] = *(const uint4*)(lp + 8);
    }
    __syncthreads();

    bf16x8 a_h[2];
    #pragma unroll
    for (int mi = 0; mi < 2; ++mi) {
      int row = wv * 32 + mi * 16 + l15;
      a_h[mi] = *(const bf16x8*)&smem[AH + row * 40 + koff];
    }
    #pragma unroll
    for (int ni = 0; ni < 8; ++ni) {
      int col = ni * 16 + l15;
      bf16x8 b_h = *(const bf16x8*)&smem[BHo + col * 40 + koff];
      bf16x8 b_l = *(const bf16x8*)&smem[BLo + col * 40 + koff];
      #pragma unroll
      for (int mi = 0; mi < 2; ++mi) {
        acc[mi][ni] = __builtin_amdgcn_mfma_f32_16x16x32_bf16(a_h[mi], b_h, acc[mi][ni], 0, 0, 0);
        acc[mi][ni] = __builtin_amdgcn_mfma_f32_16x16x32_bf16(a_h[mi], b_l, acc[mi][ni], 0, 0, 0);
      }
    }
    __syncthreads();
  }

  float g = 1.0f / (1.0f + __expf(-skip[l * 2 + nt]));

  #pragma unroll
  for (int mi = 0; mi < 2; ++mi) {
    #pragma unroll
    for (int ni = 0; ni < 8; ++ni) {
      int colL = ni * 16 + l15;
      float bi = biasBuf[biasOff + colL];
      #pragma unroll
      for (int rr = 0; rr < 4; ++rr) {
        int row = m0 + wv * 32 + mi * 16 + g4 * 4 + rr;
        float o = acc[mi][ni][rr] + bi;
        if (row < M) {
          size_t idx = (size_t)(rowbase + row) * 128 + colL;
          float xo = bf16_to_f(xh_all[idx]) + bf16_to_f(xl_all[idx]);
          o = g * o + (1.0f - g) * xo;
        }
        acc[mi][ni][rr] = o;
      }
    }
  }

  const int wrow = tid >> 2, wseg = tid & 3;
  #pragma unroll
  for (int ph = 0; ph < 2; ++ph) {
    #pragma unroll
    for (int h = 0; h < 2; ++h) {
      if (ph || h) __syncthreads();
      if ((wv >> 1) == h) {
        #pragma unroll
        for (int mi = 0; mi < 2; ++mi) {
          int rl = (wv & 1) * 32 + mi * 16 + g4 * 4;
          #pragma unroll
          for (int ni = 0; ni < 8; ++ni) {
            #pragma unroll
            for (int rr = 0; rr < 4; ++rr) {
              u16 hh, ll;
              split2(acc[mi][ni][rr], hh, ll);
              smem[(rl + rr) * 136 + ni * 16 + l15] = ph ? ll : hh;
            }
          }
        }
      }
      __syncthreads();
      int grow = m0 + h * 64 + wrow;
      if (grow < M) {
        u16* dstp = ph ? xl_all : xh_all;
        uint4* dst = (uint4*)&dstp[(size_t)(rowbase + grow) * 128 + wseg * 32];
        const uint4* src = (const uint4*)&smem[wrow * 136 + wseg * 32];
        #pragma unroll
        for (int j = 0; j < 4; ++j) dst[j] = src[j];
      }
    }
  }
}

// ---------------- merged q/kv projection: A resident in LDS across all N-slabs --------------
__global__ __launch_bounds__(256) void projN(
    const u16* __restrict__ xh_all,
    const u16* __restrict__ Bth, const float* __restrict__ biasBuf,
    u16* __restrict__ q_all, u16* __restrict__ kvA,
    u16* __restrict__ kvB1, u16* __restrict__ kvB2, int last) {
  __shared__ u16 smem[22528];  // A [128][136] @0 (34816B); B [128][40] @17408 (epi reuses)
  constexpr int AH = 0, BH = 17408;
  const int tid = threadIdx.x, lane = tid & 63, wv = tid >> 6;
  const int l15 = lane & 15, g4 = lane >> 4, koff = g4 * 8;
  const int bid = blockIdx.x;
  const int nt = (bid < NB0) ? 0 : 1;
  const int m0 = nt ? (bid - NB0) * 128 : bid * 128;
  const int M = nt ? NQ : NC;
  const int abase = nt ? NC : 0;
  const int nslab = nt ? (last ? 2 : 3) : (last ? 3 : 5);

  {
    const int sr = tid >> 1, sc = (tid & 1) * 64;
    if ((m0 + sr) < M) {
      const u16* ap = xh_all + (size_t)(abase + m0 + sr) * 128 + sc;
      #pragma unroll
      for (int j = 0; j < 8; ++j)
        *(uint4*)&smem[AH + sr * 136 + sc + j * 8] = *(const uint4*)(ap + j * 8);
    } else {
      uint4 z = {0, 0, 0, 0};
      #pragma unroll
      for (int j = 0; j < 8; ++j)
        *(uint4*)&smem[AH + sr * 136 + sc + j * 8] = z;
    }
  }

  const int srB = tid >> 1, scB = (tid & 1) * 16;
  for (int s = 0; s < nslab; ++s) {
    int y = (nt == 1 && last) ? (s + 1) : s;
    int bslab = nt ? 5 + y : y;
    u16* cp; int ld, cb, crowbase;
    if (nt == 0) {
      switch (y) {
        case 0: cp = q_all; ld = 128; cb = 0; crowbase = 0; break;
        case 1: cp = kvB1; ld = 256; cb = 0; crowbase = 0; break;
        case 2: cp = kvB1; ld = 256; cb = 128; crowbase = 0; break;
        case 3: cp = kvB2; ld = 256; cb = 0; crowbase = 0; break;
        default: cp = kvB2; ld = 256; cb = 128; crowbase = 0; break;
      }
    } else {
      switch (y) {
        case 0: cp = q_all; ld = 128; cb = 0; crowbase = NC; break;
        case 1: cp = kvA; ld = 256; cb = 0; crowbase = 0; break;
        default: cp = kvA; ld = 256; cb = 128; crowbase = 0; break;
      }
    }

    f32x4 acc[2][8];
    #pragma unroll
    for (int mi = 0; mi < 2; ++mi)
      #pragma unroll
      for (int ni = 0; ni < 8; ++ni) acc[mi][ni] = (f32x4){0.f, 0.f, 0.f, 0.f};

    #pragma unroll
    for (int ks = 0; ks < 4; ++ks) {
      const u16* bp = Bth + (size_t)(bslab * 128 + srB) * 128 + ks * 32 + scB;
      uint4 b0 = *(const uint4*)bp;
      uint4 b1 = *(const uint4*)(bp + 8);
      __syncthreads();
      *(uint4*)&smem[BH + srB * 40 + scB] = b0;
      *(uint4*)&smem[BH + srB * 40 + scB + 8] = b1;
      __syncthreads();

      bf16x8 a_h[2];
      #pragma unroll
      for (int mi = 0; mi < 2; ++mi) {
        int row = wv * 32 + mi * 16 + l15;
        a_h[mi] = *(const bf16x8*)&smem[AH + row * 136 + ks * 32 + koff];
      }
      #pragma unroll
      for (int ni = 0; ni < 8; ++ni) {
        int col = ni * 16 + l15;
        bf16x8 b_h = *(const bf16x8*)&smem[BH + col * 40 + koff];
        #pragma unroll
        for (int mi = 0; mi < 2; ++mi)
          acc[mi][ni] = __builtin_amdgcn_mfma_f32_16x16x32_bf16(a_h[mi], b_h, acc[mi][ni], 0, 0, 0);
      }
    }

    #pragma unroll
    for (int h = 0; h < 4; ++h) {
      __syncthreads();
      if (wv == h) {
        #pragma unroll
        for (int mi = 0; mi < 2; ++mi) {
          int rl = mi * 16 + g4 * 4;
          #pragma unroll
          for (int ni = 0; ni < 8; ++ni) {
            float bi = biasBuf[bslab * 128 + ni * 16 + l15];
            #pragma unroll
            for (int rr = 0; rr < 4; ++rr)
              smem[BH + (rl + rr) * 136 + ni * 16 + l15] = bf16_rne(acc[mi][ni][rr] + bi);
          }
        }
      }
      __syncthreads();
      int r = tid >> 3, cseg = (tid & 7) * 16;
      int grow = m0 + h * 32 + r;
      if (grow < M) {
        uint4* dst = (uint4*)&cp[(size_t)(crowbase + grow) * ld + cb + cseg];
        const uint4* src = (const uint4*)&smem[BH + r * 136 + cseg];
        dst[0] = src[0];
        dst[1] = src[1];
      }
    }
  }
}

// ---------------- attention: edge-per-16-lane-group, 4 edges/wave-iter, exp2 softmax --------
__device__ __forceinline__ void attn_seg(
    const u16* __restrict__ kv, int start, int end,
    const int* __restrict__ srcs, const float q8[8], int lane, float accO[8]) {
  if (start >= end) return;
  float sum = 0.0f;
  float acc[8];
  #pragma unroll
  for (int i = 0; i < 8; ++i) acc[i] = 0.0f;
  const int grp = lane >> 4;  // 0..3: which edge of the 4-in-flight
  const int j = lane & 15;    // element lane
  for (int e = start; e < end; e += 4) {
    int ee = e + grp;
    bool valid = ee < end;
    int cl = valid ? ee : end - 1;
    int s = srcs[cl];
    const u16* row = kv + (size_t)s * 256;
    uint4 uk = *(const uint4*)(row + j * 8);
    uint4 uv = *(const uint4*)(row + 128 + j * 8);
    float kr[8], vr[8];
    kr[0] = bf16_to_f((u16)(uk.x & 0xffffu)); kr[1] = bf16_to_f((u16)(uk.x >> 16));
    kr[2] = bf16_to_f((u16)(uk.y & 0xffffu)); kr[3] = bf16_to_f((u16)(uk.y >> 16));
    kr[4] = bf16_to_f((u16)(uk.z & 0xffffu)); kr[5] = bf16_to_f((u16)(uk.z >> 16));
    kr[6] = bf16_to_f((u16)(uk.w & 0xffffu)); kr[7] = bf16_to_f((u16)(uk.w >> 16));
    vr[0] = bf16_to_f((u16)(uv.x & 0xffffu)); vr[1] = bf16_to_f((u16)(uv.x >> 16));
    vr[2] = bf16_to_f((u16)(uv.y & 0xffffu)); vr[3] = bf16_to_f((u16)(uv.y >> 16));
    vr[4] = bf16_to_f((u16)(uv.z & 0xffffu)); vr[5] = bf16_to_f((u16)(uv.z >> 16));
    vr[6] = bf16_to_f((u16)(uv.w & 0xffffu)); vr[7] = bf16_to_f((u16)(uv.w >> 16));
    float p = q8[0] * kr[0];
    #pragma unroll
    for (int i = 1; i < 8; ++i) p = fmaf(q8[i], kr[i], p);
    p += __shfl_xor(p, 1);
    p += __shfl_xor(p, 2);   // all 4 lanes of head now hold head logit
    p = fminf(p, 100.0f);
    float w = valid ? exp2f(p) : 0.0f;
    sum += w;
    #pragma unroll
    for (int i = 0; i < 8; ++i) acc[i] = fmaf(w, vr[i], acc[i]);
  }
  sum += __shfl_xor(sum, 16);
  sum += __shfl_xor(sum, 32);
  #pragma unroll
  for (int i = 0; i < 8; ++i) {
    acc[i] += __shfl_xor(acc[i], 16);
    acc[i] += __shfl_xor(acc[i], 32);
  }
  float inv = 1.0f / (sum + 1e-16f);
  #pragma unroll
  for (int i = 0; i < 8; ++i) accO[i] = fmaf(acc[i], inv, accO[i]);
}

__global__ __launch_bounds__(256) void attn_all(
    const u16* __restrict__ q_all, const u16* __restrict__ kvA,
    const u16* __restrict__ kvB1, const u16* __restrict__ kvB2,
    const int* __restrict__ ptr_all, const int* __restrict__ srcs_all,
    u16* __restrict__ agg_g, int ncap) {
  int wave = threadIdx.x >> 6, lane = threadIdx.x & 63;
  int node = blockIdx.x * 4 + wave;
  if (node >= ncap) return;
  int j = lane & 15;
  float q8[8];
  {
    uint4 u = *(const uint4*)&q_all[(size_t)node * 128 + j * 8];
    q8[0] = bf16_to_f((u16)(u.x & 0xffffu)) * LOG2E; q8[1] = bf16_to_f((u16)(u.x >> 16)) * LOG2E;
    q8[2] = bf16_to_f((u16)(u.y & 0xffffu)) * LOG2E; q8[3] = bf16_to_f((u16)(u.y >> 16)) * LOG2E;
    q8[4] = bf16_to_f((u16)(u.z & 0xffffu)) * LOG2E; q8[5] = bf16_to_f((u16)(u.z >> 16)) * LOG2E;
    q8[6] = bf16_to_f((u16)(u.w & 0xffffu)) * LOG2E; q8[7] = bf16_to_f((u16)(u.w >> 16)) * LOG2E;
  }
  float accO[8];
  #pragma unroll
  for (int i = 0; i < 8; ++i) accO[i] = 0.0f;
  if (node < NC) {
    attn_seg(kvA, ptr_all[node], ptr_all[node + 1], srcs_all, q8, lane, accO);
    attn_seg(kvB1, ptr_all[NC + node], ptr_all[NC + node + 1], srcs_all, q8, lane, accO);
  } else {
    int idx = 2 * NC + (node - NC);
    attn_seg(kvB2, ptr_all[idx], ptr_all[idx + 1], srcs_all, q8, lane, accO);
  }
  if (lane < 16) {
    alignas(16) u16 hv[8];
    #pragma unroll
    for (int i = 0; i < 8; ++i) hv[i] = bf16_rne(gelu_f(accO[i]));
    *(uint4*)&agg_g[(size_t)node * 128 + j * 8] = *(const uint4*)hv;
  }
}

// ---------------- final projection ----------------
__global__ __launch_bounds__(256) void gemm_out(const u16* __restrict__ Xh,
                                                const u16* __restrict__ Xl,
                                                const float* __restrict__ W,
                                                const float* __restrict__ b,
                                                float* __restrict__ out, int M) {
  __shared__ float Ws[1024];
  __shared__ float As[32][129];
  int tid = threadIdx.x;
  int m0 = blockIdx.x * 32;
  *(float4*)&Ws[tid * 4] = *(const float4*)&W[tid * 4];
  {
    int r = tid >> 3;
    int c0 = (tid & 7) * 16;
    if (m0 + r < M) {
      const u16* hp = Xh + (size_t)(m0 + r) * 128 + c0;
      const u16* lp = Xl + (size_t)(m0 + r) * 128 + c0;
      #pragma unroll
      for (int j = 0; j < 16; ++j) As[r][c0 + j] = bf16_to_f(hp[j]) + bf16_to_f(lp[j]);
    } else {
      #pragma unroll
      for (int j = 0; j < 16; ++j) As[r][c0 + j] = 0.0f;
    }
  }
  __syncthreads();
  int r = tid >> 3, c = tid & 7;
  float sum = b[c];
  #pragma unroll 16
  for (int k = 0; k < 128; ++k) sum = fmaf(As[r][k], Ws[k * 8 + c], sum);
  if (m0 + r < M) out[(size_t)(m0 + r) * 8 + c] = sum;
}

// ---------------- host orchestration ----------------
static inline size_t align256(size_t x) { return (x + 255) & ~(size_t)255; }

extern "C" void kernel_launch(void* const* d_in, const int* in_sizes, int n_in,
                              void* d_out, int out_size, void* d_ws, size_t ws_size,
                              hipStream_t stream) {
  const float* x_context = (const float*)d_in[0];
  const float* x_question = (const float*)d_in[1];
  const int* src_q2c = (const int*)d_in[2];
  const int* dst_q2c = (const int*)d_in[3];
  const int* src_c2c = (const int*)d_in[4];
  const int* dst_c2c = (const int*)d_in[5];
  const int* src_c2q = (const int*)d_in[6];
  const int* dst_c2q = (const int*)d_in[7];
  const float* inWc = (const float*)d_in[8];
  const float* inbc = (const float*)d_in[9];
  const float* inWq = (const float*)d_in[10];
  const float* inbq = (const float*)d_in[11];
  const float* kW = (const float*)d_in[12];
  const float* kB = (const float*)d_in[13];
  const float* qW = (const float*)d_in[14];
  const float* qB = (const float*)d_in[15];
  const float* vW = (const float*)d_in[16];
  const float* vB = (const float*)d_in[17];
  const float* aW = (const float*)d_in[18];
  const float* aB = (const float*)d_in[19];
  const float* skip = (const float*)d_in[20];
  const float* arel = (const float*)d_in[21];
  const float* mrel = (const float*)d_in[22];
  const float* prel = (const float*)d_in[23];
  const float* outW = (const float*)d_in[24];
  const float* outb = (const float*)d_in[25];

  char* base = (char*)d_ws;
  size_t off = 0;
  auto carve = [&](size_t bytes) -> void* {
    void* p = base + off;
    off = align256(off + bytes);
    return p;
  };
  u16* xh_all = (u16*)carve((size_t)NTOT2 * 128 * 2);
  u16* xl_all = (u16*)carve((size_t)NTOT2 * 128 * 2);
  u16* q_all = (u16*)carve((size_t)NTOT2 * 128 * 2);
  u16* kvA = (u16*)carve((size_t)NQ * 256 * 2);
  u16* kvB1 = (u16*)carve((size_t)NC * 256 * 2);
  u16* kvB2 = (u16*)carve((size_t)NC * 256 * 2);
  u16* agg_g = (u16*)carve((size_t)NTOT2 * 128 * 2);
  u16* Bth = (u16*)carve((size_t)2560 * 128 * 2);   // 20 slabs (both layers)
  u16* Btl = (u16*)carve((size_t)2560 * 128 * 2);
  u16* BthI = (u16*)carve((size_t)(320 + 768) * 128 * 2);
  u16* BtlI = (u16*)carve((size_t)(320 + 768) * 128 * 2);
  float* biasBuf = (float*)carve(2560 * 4);
  float* biasIn = (float*)carve(256 * 4);
  int* ptr_all = (int*)carve((size_t)(NTOT + 1) * 4);
  int* srcs_all = (int*)carve((size_t)3 * NEDGE * 4);
  int* counts = (int*)carve((size_t)NTOT * 4);
  int* cursor = (int*)carve((size_t)NTOT * 4);
  int* blksums = (int*)carve(2048 * 4);

  // ---- split_in zeroes counts; prep_all counts edges (fused) ----
  split_in<<<dim3(128, 2), 256, 0, stream>>>(inWc, inbc, inWq, inbq, BthI, BtlI, biasIn, counts);
  prep_all<<<dim3(128, 20), 128, 0, stream>>>(kW, kB, qW, qB, vW, vB, aW, aB,
                                              arel, mrel, prel, Bth, Btl, biasBuf,
                                              dst_q2c, dst_c2c, dst_c2q, counts);

  // ---- scan chain ----
  {
    int nb = (NTOT + 255) / 256;
    k_scan_block<<<nb, 256, 0, stream>>>(counts, ptr_all, blksums, NTOT);
    k_scan_sums<<<1, 1024, 0, stream>>>(blksums, nb);
    k_scan_add<<<nb, 256, 0, stream>>>(ptr_all, blksums, cursor, NTOT, 3 * NEDGE);
  }

  // ---- fused scatter + input projections ----
  pipe_gemm<<<NSCAT + NBALL64, 256, 0, stream>>>(
      x_context, x_question, BthI, BtlI, biasIn, xh_all, xl_all,
      src_q2c, src_c2c, src_c2q, dst_q2c, dst_c2c, dst_c2q, cursor, srcs_all);

  for (int l = 0; l < 2; ++l) {
    const int last = (l == 1);
    const u16* BthL = Bth + (size_t)l * 10 * 128 * 128;
    const u16* BtlL = Btl + (size_t)l * 10 * 128 * 128;
    const float* biasL = biasBuf + (size_t)l * 1280;
    projN<<<NBALL, 256, 0, stream>>>(xh_all, BthL, biasL, q_all, kvA, kvB1, kvB2, last);
    int ncap = last ? NC : NTOT2;
    attn_all<<<(ncap + 3) / 4, 256, 0, stream>>>(q_all, kvA, kvB1, kvB2,
                                                 ptr_all, srcs_all, agg_g, ncap);
    aproj_gemm<<<last ? NB0 : NBALL, 256, 0, stream>>>(agg_g, BthL, BtlL, biasL,
                                                       xh_all, xl_all, skip, l);
  }

  gemm_out<<<(NC + 31) / 32, 256, 0, stream>>>(xh_all, xl_all, outW, outb, (float*)d_out, NC);
}

// Round 19
// 689.875 us; speedup vs baseline: 1.0253x; 1.0253x over previous
//
#include <hip/hip_runtime.h>

constexpr int NC = 100000;
constexpr int NQ = 20000;
constexpr int FC = 300;
constexpr int FQ = 768;
constexpr int NEDGE = 400000;
constexpr int NTOT = NC + NC + NQ;   // concatenated dst segments: et0 | et1 | et2
constexpr int NTOT2 = NC + NQ;       // all nodes (context then question)
constexpr int NB0 = (NC + 127) / 128;  // 782
constexpr int NB1 = (NQ + 127) / 128;  // 157
constexpr int NBALL = NB0 + NB1;       // 939
constexpr int NBC64 = (NC + 63) / 64;  // 1563
constexpr int NBQ64 = (NQ + 63) / 64;  // 313
constexpr int NBALL64 = NBC64 + NBQ64; // 1876
constexpr float SCALE = 0.17677669529663687f;  // 1/sqrt(32)
constexpr float LOG2E = 1.4426950408889634f;

typedef __attribute__((ext_vector_type(8))) short bf16x8;
typedef __attribute__((ext_vector_type(4))) float f32x4;
typedef unsigned short u16;

__device__ __forceinline__ float gelu_f(float x) {
  return 0.5f * x * (1.0f + erff(x * 0.7071067811865476f));
}
__device__ __forceinline__ u16 bf16_rne(float x) {
  unsigned u = __float_as_uint(x);
  unsigned r = u + 0x7fffu + ((u >> 16) & 1u);
  return (u16)(r >> 16);
}
__device__ __forceinline__ float bf16_to_f(u16 h) {
  return __uint_as_float(((unsigned)h) << 16);
}
__device__ __forceinline__ void split2(float x, u16& hi, u16& lo) {
  hi = bf16_rne(x);
  lo = bf16_rne(x - bf16_to_f(hi));
}
__device__ __forceinline__ void splitT(float x, u16& hi, u16& lo) {
  hi = (u16)(__float_as_uint(x) >> 16);
  lo = bf16_rne(x - bf16_to_f(hi));
}

// ---------------- CSR scan pieces ----------------
__global__ void k_scan_block(const int* __restrict__ in, int* __restrict__ out,
                             int* __restrict__ bsum, int n) {
  __shared__ int s[256];
  int tid = threadIdx.x;
  int i = blockIdx.x * 256 + tid;
  int v = (i < n) ? in[i] : 0;
  s[tid] = v;
  __syncthreads();
  for (int off = 1; off < 256; off <<= 1) {
    int t = (tid >= off) ? s[tid - off] : 0;
    __syncthreads();
    s[tid] += t;
    __syncthreads();
  }
  if (i < n) out[i] = s[tid] - v;
  if (tid == 255) bsum[blockIdx.x] = s[255];
}

__global__ void k_scan_sums(int* __restrict__ bsum, int nb) {
  __shared__ int s[1024];
  int tid = threadIdx.x;
  int v = (tid < nb) ? bsum[tid] : 0;
  s[tid] = v;
  __syncthreads();
  for (int off = 1; off < 1024; off <<= 1) {
    int t = (tid >= off) ? s[tid - off] : 0;
    __syncthreads();
    s[tid] += t;
    __syncthreads();
  }
  if (tid < nb) bsum[tid] = s[tid] - v;
}

__global__ void k_scan_add(int* __restrict__ ptr, const int* __restrict__ bsum,
                           int* __restrict__ cursor, int n, int total) {
  int i = blockIdx.x * 256 + threadIdx.x;
  if (i < n) {
    int v = ptr[i] + bsum[blockIdx.x];
    ptr[i] = v;
    cursor[i] = v;
  }
  if (i == 0) ptr[n] = total;
}

__global__ void k_scatter3(const int* __restrict__ s0, const int* __restrict__ s1,
                           const int* __restrict__ s2, const int* __restrict__ d0,
                           const int* __restrict__ d1, const int* __restrict__ d2,
                           int* __restrict__ cursor, int* __restrict__ srcs_out) {
  int i = blockIdx.x * 256 + threadIdx.x;
  if (i >= 3 * NEDGE) return;
  int et = i / NEDGE, e = i - et * NEDGE;
  int d = (et == 0) ? d0[e] : (et == 1) ? d1[e] : d2[e];
  int sv = (et == 0) ? s0[e] : (et == 1) ? s1[e] : s2[e];
  int base = (et == 0) ? 0 : (et == 1) ? NC : 2 * NC;
  int p = atomicAdd(&cursor[base + d], 1);
  srcs_out[p] = sv;
}

// ---------------- B prep for BOTH layers: 20 slabs + fused edge counting --------------------
__global__ void prep_all(const float* __restrict__ kW, const float* __restrict__ kB,
                         const float* __restrict__ qW, const float* __restrict__ qB,
                         const float* __restrict__ vW, const float* __restrict__ vB,
                         const float* __restrict__ aW, const float* __restrict__ aB,
                         const float* __restrict__ arel, const float* __restrict__ mrel,
                         const float* __restrict__ prel,
                         u16* __restrict__ Bth, u16* __restrict__ Btl,
                         float* __restrict__ biasOut,
                         const int* __restrict__ d0, const int* __restrict__ d1,
                         const int* __restrict__ d2, int* __restrict__ counts) {
  int i = blockIdx.x;     // input dim 0..127
  int col = threadIdx.x;  // output col 0..127
  int y = blockIdx.y;     // 0..19
  // fused edge counting (counts zeroed by split_in, which runs before this kernel)
  {
    const int nth = 20 * 128 * 128;
    int gtid = (y * 128 + i) * 128 + col;
    for (int e = gtid; e < 3 * NEDGE; e += nth) {
      int et = e / NEDGE, ee = e - et * NEDGE;
      int d = (et == 0) ? d0[ee] : (et == 1) ? d1[ee] : d2[ee];
      int base = (et == 0) ? 0 : (et == 1) ? NC : 2 * NC;
      atomicAdd(&counts[base + d], 1);
    }
  }
  int l = y / 10, yy = y % 10;
  size_t lw = (size_t)l * 2 * 16384, lb = (size_t)l * 2 * 128;
  size_t le = (size_t)l * 3 * 4096, lp = (size_t)l * 3 * 4;
  const float *W = nullptr, *bb = nullptr, *rel = nullptr, *pr = nullptr;
  float mscale = 1.0f;
  bool fold = false;
  switch (yy) {
    case 0: W = qW + lw; bb = qB + lb; break;
    case 1: fold = true; W = kW + lw; bb = kB + lb; rel = arel + le + 4096; pr = prel + lp + 4; mscale = SCALE; break;
    case 2: fold = true; W = vW + lw; bb = vB + lb; rel = mrel + le + 4096; break;
    case 3: fold = true; W = kW + lw; bb = kB + lb; rel = arel + le + 8192; pr = prel + lp + 8; mscale = SCALE; break;
    case 4: fold = true; W = vW + lw; bb = vB + lb; rel = mrel + le + 8192; break;
    case 5: W = qW + lw + 16384; bb = qB + lb + 128; break;
    case 6: fold = true; W = kW + lw + 16384; bb = kB + lb + 128; rel = arel + le; pr = prel + lp; mscale = SCALE; break;
    case 7: fold = true; W = vW + lw + 16384; bb = vB + lb + 128; rel = mrel + le; break;
    case 8: W = aW + lw; bb = aB + lb; break;
    default: W = aW + lw + 16384; bb = aB + lb + 128; break;
  }
  int colOff = y * 128;
  if (!fold) {
    float v = W[i * 128 + col];
    u16 hi, lo;
    split2(v, hi, lo);
    Bth[(size_t)(colOff + col) * 128 + i] = hi;
    Btl[(size_t)(colOff + col) * 128 + i] = lo;
    if (i == 0) biasOut[colOff + col] = bb[col];
    return;
  }
  int h = col >> 5, f = col & 31;
  float m = (pr ? pr[h] : 1.0f) * mscale;
  float s = 0.0f;
  #pragma unroll
  for (int d = 0; d < 32; ++d)
    s += W[i * 128 + h * 32 + d] * rel[(h * 32 + d) * 32 + f];
  s *= m;
  u16 hi, lo;
  split2(s, hi, lo);
  Bth[(size_t)(colOff + col) * 128 + i] = hi;
  Btl[(size_t)(colOff + col) * 128 + i] = lo;
  if (i == 0) {
    float sb = 0.0f;
    #pragma unroll
    for (int d = 0; d < 32; ++d)
      sb += bb[h * 32 + d] * rel[(h * 32 + d) * 32 + f];
    biasOut[colOff + col] = sb * m;
  }
}

// ---------------- input weight split (+ zeroes counts for the fused counting) ---------------
__global__ void split_in(const float* __restrict__ Wc, const float* __restrict__ bc,
                         const float* __restrict__ Wq, const float* __restrict__ bq,
                         u16* __restrict__ Bth, u16* __restrict__ Btl,
                         float* __restrict__ biasOut, int* __restrict__ counts) {
  int n = blockIdx.x, y = blockIdx.y;
  {
    const int nth = 2 * 128 * 256;
    int gtid = (y * 128 + n) * 256 + threadIdx.x;
    for (int i = gtid; i < NTOT; i += nth) counts[i] = 0;
  }
  const float* W = y ? Wq : Wc;
  const float* b = y ? bq : bc;
  int K = y ? FQ : FC, Kp = y ? 768 : 320;
  size_t boff = y ? (size_t)128 * 320 : 0;
  for (int k = threadIdx.x; k < Kp; k += 256) {
    float v = (k < K) ? W[(size_t)k * 128 + n] : 0.0f;
    u16 hi, lo;
    split2(v, hi, lo);
    Bth[boff + (size_t)n * Kp + k] = hi;
    Btl[boff + (size_t)n * Kp + k] = lo;
  }
  if (threadIdx.x == 0) biasOut[(y ? 128 : 0) + n] = b[n];
}

// ---------------- input projection: f32 A, BM=64, 3-term split, named A-2deep/B-1deep -------
__global__ __launch_bounds__(256) void pipe_gemm(
    const float* __restrict__ Ac, const float* __restrict__ Aq,
    const u16* __restrict__ Bth, const u16* __restrict__ Btl,
    const float* __restrict__ biasBuf,
    u16* __restrict__ xh_all, u16* __restrict__ xl_all) {
  __shared__ u16 smem[15360];  // Ah@0 Al@2560 Bh@5120 Bl@10240 ; epilogue reuses @0 [64][136]
  constexpr int AH = 0, AL = 2560, BH = 5120, BL = 10240;
  const int tid = threadIdx.x, lane = tid & 63, wv = tid >> 6;
  const int l15 = lane & 15, g4 = lane >> 4, koff = g4 * 8;
  const int srA = tid >> 2, scA = (tid & 3) * 8;   // A: 8 f32/thread
  const int srB = tid >> 1, scB = (tid & 1) * 16;  // B: 16 u16/thread/array

  const int bid = blockIdx.x;
  const int nt = (bid < NBC64) ? 0 : 1;
  const int m0 = nt ? (bid - NBC64) * 64 : bid * 64;
  const int M = nt ? NQ : NC;
  const int rowbase = nt ? NC : 0;
  const float* A32;
  int K, Kp, biasOff;
  size_t boff;
  if (nt == 0) { A32 = Ac; K = FC; Kp = 320; boff = 0; biasOff = 0; }
  else { A32 = Aq; K = FQ; Kp = 768; boff = (size_t)128 * 320; biasOff = 128; }
  size_t arow = (size_t)(m0 + srA) * K;
  const bool rowokA = (m0 + srA) < M;
  const int nk = (K + 31) / 32;

  f32x4 acc[8];
  #pragma unroll
  for (int ni = 0; ni < 8; ++ni) acc[ni] = (f32x4){0.f, 0.f, 0.f, 0.f};

  auto loadA = [&](float va[8], int k0) {
    if (rowokA && (k0 + 32 <= K)) {
      const float* ap = A32 + arow + k0 + scA;
      float4 f0 = *(const float4*)ap;
      float4 f1 = *(const float4*)(ap + 4);
      va[0] = f0.x; va[1] = f0.y; va[2] = f0.z; va[3] = f0.w;
      va[4] = f1.x; va[5] = f1.y; va[6] = f1.z; va[7] = f1.w;
    } else {
      #pragma unroll
      for (int j = 0; j < 8; ++j) {
        int kc = k0 + scA + j;
        va[j] = (rowokA && kc < K) ? A32[arow + kc] : 0.0f;
      }
    }
  };
  auto loadB = [&](uint4& bh0, uint4& bh1, uint4& bl0, uint4& bl1, int k0) {
    const u16* bp = Bth + boff + (size_t)srB * Kp + k0 + scB;
    bh0 = *(const uint4*)bp;
    bh1 = *(const uint4*)(bp + 8);
    const u16* lp = Btl + boff + (size_t)srB * Kp + k0 + scB;
    bl0 = *(const uint4*)lp;
    bl1 = *(const uint4*)(lp + 8);
  };

  float vaC[8], vaN[8], vaN2[8];
  uint4 bhC0, bhC1, blC0, blC1, bhN0, bhN1, blN0, blN1;
  loadA(vaC, 0);
  loadB(bhC0, bhC1, blC0, blC1, 0);
  if (nk > 1) loadA(vaN, 32);

  for (int ks = 0; ks < nk; ++ks) {
    {
      alignas(16) u16 hv[8], lv[8];
      #pragma unroll
      for (int j = 0; j < 8; ++j) splitT(vaC[j], hv[j], lv[j]);
      *(uint4*)&smem[AH + srA * 40 + scA] = *(const uint4*)hv;
      *(uint4*)&smem[AL + srA * 40 + scA] = *(const uint4*)lv;
      *(uint4*)&smem[BH + srB * 40 + scB] = bhC0;
      *(uint4*)&smem[BH + srB * 40 + scB + 8] = bhC1;
      *(uint4*)&smem[BL + srB * 40 + scB] = blC0;
      *(uint4*)&smem[BL + srB * 40 + scB + 8] = blC1;
    }
    __syncthreads();

    const bool moreA2 = (ks + 2) < nk;
    const bool moreB = (ks + 1) < nk;
    if (moreA2) loadA(vaN2, (ks + 2) * 32);
    if (moreB) loadB(bhN0, bhN1, blN0, blN1, (ks + 1) * 32);

    {
      int row = wv * 16 + l15;
      bf16x8 a_h = *(const bf16x8*)&smem[AH + row * 40 + koff];
      bf16x8 a_l = *(const bf16x8*)&smem[AL + row * 40 + koff];
      #pragma unroll
      for (int ni = 0; ni < 8; ++ni) {
        int col = ni * 16 + l15;
        bf16x8 b_h = *(const bf16x8*)&smem[BH + col * 40 + koff];
        bf16x8 b_l = *(const bf16x8*)&smem[BL + col * 40 + koff];
        acc[ni] = __builtin_amdgcn_mfma_f32_16x16x32_bf16(a_h, b_h, acc[ni], 0, 0, 0);
        acc[ni] = __builtin_amdgcn_mfma_f32_16x16x32_bf16(a_l, b_h, acc[ni], 0, 0, 0);
        acc[ni] = __builtin_amdgcn_mfma_f32_16x16x32_bf16(a_h, b_l, acc[ni], 0, 0, 0);
      }
    }
    __syncthreads();

    if (moreB) {
      #pragma unroll
      for (int j = 0; j < 8; ++j) vaC[j] = vaN[j];
      bhC0 = bhN0; bhC1 = bhN1; blC0 = blN0; blC1 = blN1;
    }
    if (moreA2) {
      #pragma unroll
      for (int j = 0; j < 8; ++j) vaN[j] = vaN2[j];
    }
  }

  const int rl0 = wv * 16 + g4 * 4;
  #pragma unroll
  for (int ni = 0; ni < 8; ++ni) {
    float bi = biasBuf[biasOff + ni * 16 + l15];
    #pragma unroll
    for (int rr = 0; rr < 4; ++rr)
      acc[ni][rr] = fmaxf(acc[ni][rr] + bi, 0.0f);
  }

  const int wrow = tid >> 2, wseg = tid & 3;
  #pragma unroll
  for (int ph = 0; ph < 2; ++ph) {
    if (ph) __syncthreads();
    #pragma unroll
    for (int ni = 0; ni < 8; ++ni) {
      #pragma unroll
      for (int rr = 0; rr < 4; ++rr) {
        u16 hh, ll;
        split2(acc[ni][rr], hh, ll);
        smem[(rl0 + rr) * 136 + ni * 16 + l15] = ph ? ll : hh;
      }
    }
    __syncthreads();
    int grow = m0 + wrow;
    if (grow < M) {
      u16* dstp = ph ? xl_all : xh_all;
      uint4* dst = (uint4*)&dstp[(size_t)(rowbase + grow) * 128 + wseg * 32];
      const uint4* src = (const uint4*)&smem[wrow * 136 + wseg * 32];
      #pragma unroll
      for (int j = 0; j < 4; ++j) dst[j] = src[j];
    }
  }
}

// ---------------- a-projection GEMM: pre-gelu'd bf16 A (from attn), 2-term B, skip-gate -----
__global__ __launch_bounds__(256) void aproj_gemm(
    const u16* __restrict__ Ag,     // gelu(agg) bf16 [NTOT2 x 128]
    const u16* __restrict__ Bth, const u16* __restrict__ Btl,
    const float* __restrict__ biasBuf,
    u16* __restrict__ xh_all, u16* __restrict__ xl_all,
    const float* __restrict__ skip, int l) {
  __shared__ u16 smem[15360];  // Ah@0, Bh@5120, Bl@10240; epilogue reuses [64][136]
  constexpr int AH = 0, BHo = 5120, BLo = 10240;
  const int tid = threadIdx.x, lane = tid & 63, wv = tid >> 6;
  const int l15 = lane & 15, g4 = lane >> 4, koff = g4 * 8;
  const int sr = tid >> 1, sc = (tid & 1) * 16;

  const int bid = blockIdx.x;
  const int nt = (bid < NB0) ? 0 : 1;
  const int m0 = nt ? (bid - NB0) * 128 : bid * 128;
  const int M = nt ? NQ : NC;
  const int rowbase = nt ? NC : 0;
  const size_t boff = (size_t)(8 + nt) * 16384;
  const int biasOff = (8 + nt) * 128;
  const bool rowok = (m0 + sr) < M;

  f32x4 acc[2][8];
  #pragma unroll
  for (int mi = 0; mi < 2; ++mi)
    #pragma unroll
    for (int ni = 0; ni < 8; ++ni) acc[mi][ni] = (f32x4){0.f, 0.f, 0.f, 0.f};

  for (int k0 = 0; k0 < 128; k0 += 32) {
    uint4 h0 = {0, 0, 0, 0}, h1 = {0, 0, 0, 0};
    if (rowok) {
      const u16* ap = Ag + (size_t)(rowbase + m0 + sr) * 128 + k0 + sc;
      h0 = *(const uint4*)ap;
      h1 = *(const uint4*)(ap + 8);
    }
    *(uint4*)&smem[AH + sr * 40 + sc] = h0;
    *(uint4*)&smem[AH + sr * 40 + sc + 8] = h1;
    {
      const u16* bp = Bth + boff + (size_t)sr * 128 + k0 + sc;
      *(uint4*)&smem[BHo + sr * 40 + sc] = *(const uint4*)bp;
      *(uint4*)&smem[BHo + sr * 40 + sc + 8] = *(const uint4*)(bp + 8);
      const u16* lp = Btl + boff + (size_t)sr * 128 + k0 + sc;
      *(uint4*)&smem[BLo + sr * 40 + sc] = *(const uint4*)lp;
      *(uint4*)&smem[BLo + sr * 40 + sc + 8] = *(const uint4*)(lp + 8);
    }
    __syncthreads();

    bf16x8 a_h[2];
    #pragma unroll
    for (int mi = 0; mi < 2; ++mi) {
      int row = wv * 32 + mi * 16 + l15;
      a_h[mi] = *(const bf16x8*)&smem[AH + row * 40 + koff];
    }
    #pragma unroll
    for (int ni = 0; ni < 8; ++ni) {
      int col = ni * 16 + l15;
      bf16x8 b_h = *(const bf16x8*)&smem[BHo + col * 40 + koff];
      bf16x8 b_l = *(const bf16x8*)&smem[BLo + col * 40 + koff];
      #pragma unroll
      for (int mi = 0; mi < 2; ++mi) {
        acc[mi][ni] = __builtin_amdgcn_mfma_f32_16x16x32_bf16(a_h[mi], b_h, acc[mi][ni], 0, 0, 0);
        acc[mi][ni] = __builtin_amdgcn_mfma_f32_16x16x32_bf16(a_h[mi], b_l, acc[mi][ni], 0, 0, 0);
      }
    }
    __syncthreads();
  }

  float g = 1.0f / (1.0f + __expf(-skip[l * 2 + nt]));

  #pragma unroll
  for (int mi = 0; mi < 2; ++mi) {
    #pragma unroll
    for (int ni = 0; ni < 8; ++ni) {
      int colL = ni * 16 + l15;
      float bi = biasBuf[biasOff + colL];
      #pragma unroll
      for (int rr = 0; rr < 4; ++rr) {
        int row = m0 + wv * 32 + mi * 16 + g4 * 4 + rr;
        float o = acc[mi][ni][rr] + bi;
        if (row < M) {
          size_t idx = (size_t)(rowbase + row) * 128 + colL;
          float xo = bf16_to_f(xh_all[idx]) + bf16_to_f(xl_all[idx]);
          o = g * o + (1.0f - g) * xo;
        }
        acc[mi][ni][rr] = o;
      }
    }
  }

  const int wrow = tid >> 2, wseg = tid & 3;
  #pragma unroll
  for (int ph = 0; ph < 2; ++ph) {
    #pragma unroll
    for (int h = 0; h < 2; ++h) {
      if (ph || h) __syncthreads();
      if ((wv >> 1) == h) {
        #pragma unroll
        for (int mi = 0; mi < 2; ++mi) {
          int rl = (wv & 1) * 32 + mi * 16 + g4 * 4;
          #pragma unroll
          for (int ni = 0; ni < 8; ++ni) {
            #pragma unroll
            for (int rr = 0; rr < 4; ++rr) {
              u16 hh, ll;
              split2(acc[mi][ni][rr], hh, ll);
              smem[(rl + rr) * 136 + ni * 16 + l15] = ph ? ll : hh;
            }
          }
        }
      }
      __syncthreads();
      int grow = m0 + h * 64 + wrow;
      if (grow < M) {
        u16* dstp = ph ? xl_all : xh_all;
        uint4* dst = (uint4*)&dstp[(size_t)(rowbase + grow) * 128 + wseg * 32];
        const uint4* src = (const uint4*)&smem[wrow * 136 + wseg * 32];
        #pragma unroll
        for (int j = 0; j < 4; ++j) dst[j] = src[j];
      }
    }
  }
}

// ---------------- merged q/kv projection: A resident in LDS across all N-slabs --------------
__global__ __launch_bounds__(256) void projN(
    const u16* __restrict__ xh_all,
    const u16* __restrict__ Bth, const float* __restrict__ biasBuf,
    u16* __restrict__ q_all, u16* __restrict__ kvA,
    u16* __restrict__ kvB1, u16* __restrict__ kvB2, int last) {
  __shared__ u16 smem[22528];  // A [128][136] @0 (34816B); B [128][40] @17408 (epi reuses)
  constexpr int AH = 0, BH = 17408;
  const int tid = threadIdx.x, lane = tid & 63, wv = tid >> 6;
  const int l15 = lane & 15, g4 = lane >> 4, koff = g4 * 8;
  const int bid = blockIdx.x;
  const int nt = (bid < NB0) ? 0 : 1;
  const int m0 = nt ? (bid - NB0) * 128 : bid * 128;
  const int M = nt ? NQ : NC;
  const int abase = nt ? NC : 0;
  const int nslab = nt ? (last ? 2 : 3) : (last ? 3 : 5);

  {
    const int sr = tid >> 1, sc = (tid & 1) * 64;
    if ((m0 + sr) < M) {
      const u16* ap = xh_all + (size_t)(abase + m0 + sr) * 128 + sc;
      #pragma unroll
      for (int j = 0; j < 8; ++j)
        *(uint4*)&smem[AH + sr * 136 + sc + j * 8] = *(const uint4*)(ap + j * 8);
    } else {
      uint4 z = {0, 0, 0, 0};
      #pragma unroll
      for (int j = 0; j < 8; ++j)
        *(uint4*)&smem[AH + sr * 136 + sc + j * 8] = z;
    }
  }

  const int srB = tid >> 1, scB = (tid & 1) * 16;
  for (int s = 0; s < nslab; ++s) {
    int y = (nt == 1 && last) ? (s + 1) : s;
    int bslab = nt ? 5 + y : y;
    u16* cp; int ld, cb, crowbase;
    if (nt == 0) {
      switch (y) {
        case 0: cp = q_all; ld = 128; cb = 0; crowbase = 0; break;
        case 1: cp = kvB1; ld = 256; cb = 0; crowbase = 0; break;
        case 2: cp = kvB1; ld = 256; cb = 128; crowbase = 0; break;
        case 3: cp = kvB2; ld = 256; cb = 0; crowbase = 0; break;
        default: cp = kvB2; ld = 256; cb = 128; crowbase = 0; break;
      }
    } else {
      switch (y) {
        case 0: cp = q_all; ld = 128; cb = 0; crowbase = NC; break;
        case 1: cp = kvA; ld = 256; cb = 0; crowbase = 0; break;
        default: cp = kvA; ld = 256; cb = 128; crowbase = 0; break;
      }
    }

    f32x4 acc[2][8];
    #pragma unroll
    for (int mi = 0; mi < 2; ++mi)
      #pragma unroll
      for (int ni = 0; ni < 8; ++ni) acc[mi][ni] = (f32x4){0.f, 0.f, 0.f, 0.f};

    #pragma unroll
    for (int ks = 0; ks < 4; ++ks) {
      const u16* bp = Bth + (size_t)(bslab * 128 + srB) * 128 + ks * 32 + scB;
      uint4 b0 = *(const uint4*)bp;
      uint4 b1 = *(const uint4*)(bp + 8);
      __syncthreads();
      *(uint4*)&smem[BH + srB * 40 + scB] = b0;
      *(uint4*)&smem[BH + srB * 40 + scB + 8] = b1;
      __syncthreads();

      bf16x8 a_h[2];
      #pragma unroll
      for (int mi = 0; mi < 2; ++mi) {
        int row = wv * 32 + mi * 16 + l15;
        a_h[mi] = *(const bf16x8*)&smem[AH + row * 136 + ks * 32 + koff];
      }
      #pragma unroll
      for (int ni = 0; ni < 8; ++ni) {
        int col = ni * 16 + l15;
        bf16x8 b_h = *(const bf16x8*)&smem[BH + col * 40 + koff];
        #pragma unroll
        for (int mi = 0; mi < 2; ++mi)
          acc[mi][ni] = __builtin_amdgcn_mfma_f32_16x16x32_bf16(a_h[mi], b_h, acc[mi][ni], 0, 0, 0);
      }
    }

    #pragma unroll
    for (int h = 0; h < 4; ++h) {
      __syncthreads();
      if (wv == h) {
        #pragma unroll
        for (int mi = 0; mi < 2; ++mi) {
          int rl = mi * 16 + g4 * 4;
          #pragma unroll
          for (int ni = 0; ni < 8; ++ni) {
            float bi = biasBuf[bslab * 128 + ni * 16 + l15];
            #pragma unroll
            for (int rr = 0; rr < 4; ++rr)
              smem[BH + (rl + rr) * 136 + ni * 16 + l15] = bf16_rne(acc[mi][ni][rr] + bi);
          }
        }
      }
      __syncthreads();
      int r = tid >> 3, cseg = (tid & 7) * 16;
      int grow = m0 + h * 32 + r;
      if (grow < M) {
        uint4* dst = (uint4*)&cp[(size_t)(crowbase + grow) * ld + cb + cseg];
        const uint4* src = (const uint4*)&smem[BH + r * 136 + cseg];
        dst[0] = src[0];
        dst[1] = src[1];
      }
    }
  }
}

// ---------------- attention: edge-per-16-lane-group, 4 edges/wave-iter, exp2 softmax --------
__device__ __forceinline__ void attn_seg(
    const u16* __restrict__ kv, int start, int end,
    const int* __restrict__ srcs, const float q8[8], int lane, float accO[8]) {
  if (start >= end) return;
  float sum = 0.0f;
  float acc[8];
  #pragma unroll
  for (int i = 0; i < 8; ++i) acc[i] = 0.0f;
  const int grp = lane >> 4;  // 0..3: which edge of the 4-in-flight
  const int j = lane & 15;    // element lane
  for (int e = start; e < end; e += 4) {
    int ee = e + grp;
    bool valid = ee < end;
    int cl = valid ? ee : end - 1;
    int s = srcs[cl];
    const u16* row = kv + (size_t)s * 256;
    uint4 uk = *(const uint4*)(row + j * 8);
    uint4 uv = *(const uint4*)(row + 128 + j * 8);
    float kr[8], vr[8];
    kr[0] = bf16_to_f((u16)(uk.x & 0xffffu)); kr[1] = bf16_to_f((u16)(uk.x >> 16));
    kr[2] = bf16_to_f((u16)(uk.y & 0xffffu)); kr[3] = bf16_to_f((u16)(uk.y >> 16));
    kr[4] = bf16_to_f((u16)(uk.z & 0xffffu)); kr[5] = bf16_to_f((u16)(uk.z >> 16));
    kr[6] = bf16_to_f((u16)(uk.w & 0xffffu)); kr[7] = bf16_to_f((u16)(uk.w >> 16));
    vr[0] = bf16_to_f((u16)(uv.x & 0xffffu)); vr[1] = bf16_to_f((u16)(uv.x >> 16));
    vr[2] = bf16_to_f((u16)(uv.y & 0xffffu)); vr[3] = bf16_to_f((u16)(uv.y >> 16));
    vr[4] = bf16_to_f((u16)(uv.z & 0xffffu)); vr[5] = bf16_to_f((u16)(uv.z >> 16));
    vr[6] = bf16_to_f((u16)(uv.w & 0xffffu)); vr[7] = bf16_to_f((u16)(uv.w >> 16));
    float p = q8[0] * kr[0];
    #pragma unroll
    for (int i = 1; i < 8; ++i) p = fmaf(q8[i], kr[i], p);
    p += __shfl_xor(p, 1);
    p += __shfl_xor(p, 2);   // all 4 lanes of head now hold head logit
    p = fminf(p, 100.0f);
    float w = valid ? exp2f(p) : 0.0f;
    sum += w;
    #pragma unroll
    for (int i = 0; i < 8; ++i) acc[i] = fmaf(w, vr[i], acc[i]);
  }
  sum += __shfl_xor(sum, 16);
  sum += __shfl_xor(sum, 32);
  #pragma unroll
  for (int i = 0; i < 8; ++i) {
    acc[i] += __shfl_xor(acc[i], 16);
    acc[i] += __shfl_xor(acc[i], 32);
  }
  float inv = 1.0f / (sum + 1e-16f);
  #pragma unroll
  for (int i = 0; i < 8; ++i) accO[i] = fmaf(acc[i], inv, accO[i]);
}

__global__ __launch_bounds__(256) void attn_all(
    const u16* __restrict__ q_all, const u16* __restrict__ kvA,
    const u16* __restrict__ kvB1, const u16* __restrict__ kvB2,
    const int* __restrict__ ptr_all, const int* __restrict__ srcs_all,
    u16* __restrict__ agg_g, int ncap) {
  int wave = threadIdx.x >> 6, lane = threadIdx.x & 63;
  int node = blockIdx.x * 4 + wave;
  if (node >= ncap) return;
  int j = lane & 15;
  float q8[8];
  {
    uint4 u = *(const uint4*)&q_all[(size_t)node * 128 + j * 8];
    q8[0] = bf16_to_f((u16)(u.x & 0xffffu)) * LOG2E; q8[1] = bf16_to_f((u16)(u.x >> 16)) * LOG2E;
    q8[2] = bf16_to_f((u16)(u.y & 0xffffu)) * LOG2E; q8[3] = bf16_to_f((u16)(u.y >> 16)) * LOG2E;
    q8[4] = bf16_to_f((u16)(u.z & 0xffffu)) * LOG2E; q8[5] = bf16_to_f((u16)(u.z >> 16)) * LOG2E;
    q8[6] = bf16_to_f((u16)(u.w & 0xffffu)) * LOG2E; q8[7] = bf16_to_f((u16)(u.w >> 16)) * LOG2E;
  }
  float accO[8];
  #pragma unroll
  for (int i = 0; i < 8; ++i) accO[i] = 0.0f;
  if (node < NC) {
    attn_seg(kvA, ptr_all[node], ptr_all[node + 1], srcs_all, q8, lane, accO);
    attn_seg(kvB1, ptr_all[NC + node], ptr_all[NC + node + 1], srcs_all, q8, lane, accO);
  } else {
    int idx = 2 * NC + (node - NC);
    attn_seg(kvB2, ptr_all[idx], ptr_all[idx + 1], srcs_all, q8, lane, accO);
  }
  if (lane < 16) {
    alignas(16) u16 hv[8];
    #pragma unroll
    for (int i = 0; i < 8; ++i) hv[i] = bf16_rne(gelu_f(accO[i]));
    *(uint4*)&agg_g[(size_t)node * 128 + j * 8] = *(const uint4*)hv;
  }
}

// ---------------- final projection ----------------
__global__ __launch_bounds__(256) void gemm_out(const u16* __restrict__ Xh,
                                                const u16* __restrict__ Xl,
                                                const float* __restrict__ W,
                                                const float* __restrict__ b,
                                                float* __restrict__ out, int M) {
  __shared__ float Ws[1024];
  __shared__ float As[32][129];
  int tid = threadIdx.x;
  int m0 = blockIdx.x * 32;
  *(float4*)&Ws[tid * 4] = *(const float4*)&W[tid * 4];
  {
    int r = tid >> 3;
    int c0 = (tid & 7) * 16;
    if (m0 + r < M) {
      const u16* hp = Xh + (size_t)(m0 + r) * 128 + c0;
      const u16* lp = Xl + (size_t)(m0 + r) * 128 + c0;
      #pragma unroll
      for (int j = 0; j < 16; ++j) As[r][c0 + j] = bf16_to_f(hp[j]) + bf16_to_f(lp[j]);
    } else {
      #pragma unroll
      for (int j = 0; j < 16; ++j) As[r][c0 + j] = 0.0f;
    }
  }
  __syncthreads();
  int r = tid >> 3, c = tid & 7;
  float sum = b[c];
  #pragma unroll 16
  for (int k = 0; k < 128; ++k) sum = fmaf(As[r][k], Ws[k * 8 + c], sum);
  if (m0 + r < M) out[(size_t)(m0 + r) * 8 + c] = sum;
}

// ---------------- host orchestration ----------------
static inline size_t align256(size_t x) { return (x + 255) & ~(size_t)255; }

extern "C" void kernel_launch(void* const* d_in, const int* in_sizes, int n_in,
                              void* d_out, int out_size, void* d_ws, size_t ws_size,
                              hipStream_t stream) {
  const float* x_context = (const float*)d_in[0];
  const float* x_question = (const float*)d_in[1];
  const int* src_q2c = (const int*)d_in[2];
  const int* dst_q2c = (const int*)d_in[3];
  const int* src_c2c = (const int*)d_in[4];
  const int* dst_c2c = (const int*)d_in[5];
  const int* src_c2q = (const int*)d_in[6];
  const int* dst_c2q = (const int*)d_in[7];
  const float* inWc = (const float*)d_in[8];
  const float* inbc = (const float*)d_in[9];
  const float* inWq = (const float*)d_in[10];
  const float* inbq = (const float*)d_in[11];
  const float* kW = (const float*)d_in[12];
  const float* kB = (const float*)d_in[13];
  const float* qW = (const float*)d_in[14];
  const float* qB = (const float*)d_in[15];
  const float* vW = (const float*)d_in[16];
  const float* vB = (const float*)d_in[17];
  const float* aW = (const float*)d_in[18];
  const float* aB = (const float*)d_in[19];
  const float* skip = (const float*)d_in[20];
  const float* arel = (const float*)d_in[21];
  const float* mrel = (const float*)d_in[22];
  const float* prel = (const float*)d_in[23];
  const float* outW = (const float*)d_in[24];
  const float* outb = (const float*)d_in[25];

  char* base = (char*)d_ws;
  size_t off = 0;
  auto carve = [&](size_t bytes) -> void* {
    void* p = base + off;
    off = align256(off + bytes);
    return p;
  };
  u16* xh_all = (u16*)carve((size_t)NTOT2 * 128 * 2);
  u16* xl_all = (u16*)carve((size_t)NTOT2 * 128 * 2);
  u16* q_all = (u16*)carve((size_t)NTOT2 * 128 * 2);
  u16* kvA = (u16*)carve((size_t)NQ * 256 * 2);
  u16* kvB1 = (u16*)carve((size_t)NC * 256 * 2);
  u16* kvB2 = (u16*)carve((size_t)NC * 256 * 2);
  u16* agg_g = (u16*)carve((size_t)NTOT2 * 128 * 2);
  u16* Bth = (u16*)carve((size_t)2560 * 128 * 2);   // 20 slabs (both layers)
  u16* Btl = (u16*)carve((size_t)2560 * 128 * 2);
  u16* BthI = (u16*)carve((size_t)(320 + 768) * 128 * 2);
  u16* BtlI = (u16*)carve((size_t)(320 + 768) * 128 * 2);
  float* biasBuf = (float*)carve(2560 * 4);
  float* biasIn = (float*)carve(256 * 4);
  int* ptr_all = (int*)carve((size_t)(NTOT + 1) * 4);
  int* srcs_all = (int*)carve((size_t)3 * NEDGE * 4);
  int* counts = (int*)carve((size_t)NTOT * 4);
  int* cursor = (int*)carve((size_t)NTOT * 4);
  int* blksums = (int*)carve(2048 * 4);

  // ---- split_in zeroes counts; prep_all counts edges (fused) ----
  split_in<<<dim3(128, 2), 256, 0, stream>>>(inWc, inbc, inWq, inbq, BthI, BtlI, biasIn, counts);
  prep_all<<<dim3(128, 20), 128, 0, stream>>>(kW, kB, qW, qB, vW, vB, aW, aB,
                                              arel, mrel, prel, Bth, Btl, biasBuf,
                                              dst_q2c, dst_c2c, dst_c2q, counts);

  // ---- scan chain + standalone scatter ----
  {
    int nb = (NTOT + 255) / 256;
    k_scan_block<<<nb, 256, 0, stream>>>(counts, ptr_all, blksums, NTOT);
    k_scan_sums<<<1, 1024, 0, stream>>>(blksums, nb);
    k_scan_add<<<nb, 256, 0, stream>>>(ptr_all, blksums, cursor, NTOT, 3 * NEDGE);
    k_scatter3<<<(3 * NEDGE + 255) / 256, 256, 0, stream>>>(
        src_q2c, src_c2c, src_c2q, dst_q2c, dst_c2c, dst_c2q, cursor, srcs_all);
  }

  // ---- input projections (BM=64, named prefetch) ----
  pipe_gemm<<<NBALL64, 256, 0, stream>>>(x_context, x_question, BthI, BtlI, biasIn,
                                         xh_all, xl_all);

  for (int l = 0; l < 2; ++l) {
    const int last = (l == 1);
    const u16* BthL = Bth + (size_t)l * 10 * 128 * 128;
    const u16* BtlL = Btl + (size_t)l * 10 * 128 * 128;
    const float* biasL = biasBuf + (size_t)l * 1280;
    projN<<<NBALL, 256, 0, stream>>>(xh_all, BthL, biasL, q_all, kvA, kvB1, kvB2, last);
    int ncap = last ? NC : NTOT2;
    attn_all<<<(ncap + 3) / 4, 256, 0, stream>>>(q_all, kvA, kvB1, kvB2,
                                                 ptr_all, srcs_all, agg_g, ncap);
    aproj_gemm<<<last ? NB0 : NBALL, 256, 0, stream>>>(agg_g, BthL, BtlL, biasL,
                                                       xh_all, xl_all, skip, l);
  }

  gemm_out<<<(NC + 31) / 32, 256, 0, stream>>>(xh_all, xl_all, outW, outb, (float*)d_out, NC);
}